// Round 7
// baseline (871.402 us; speedup 1.0000x reference)
//
#include <hip/hip_runtime.h>
#include <hip/hip_bf16.h>

#define NTOK 49
#define DIMC 384
#define NH 12
#define QSCALE 0.17677669529663687f

typedef __attribute__((ext_vector_type(8))) short short8;
typedef __attribute__((ext_vector_type(4))) float f32x4;
typedef unsigned int u32;

// ---------------- LDS layout for fused kernel (short units) ----------------
// STG: 3 bufs x 12 frags x 512 = 18432 (36 KB)
// KS : 2 win x [64 tok][32 dim] swz 64B rows  = 4096
// VT : 2 win x [32 dim][64 tok] swz 128B rows = 4096
// PS : 4 waves x [16][64] swz 128B rows       = 4096
// QA : 8 slabs (wave x stripe) [16][32] 64B   = 4096
// BT : 2028 -> 2032 ; QB : 1152  => 38000 sh = 76000 B -> 2 blocks/CU
#define STG_OFF 0
#define KS_OFF  18432
#define VT_OFF  22528
#define PS_OFF  26624
#define QA_OFF  30720
#define BT_OFF  34816
#define QB_OFF  36848
#define SL_TOT  38000

#define NQFRAG (NH * 6 * 12)               // 864 qkv fragments
#define WQB_SHORTS (NQFRAG * 512)          // 884736 B
#define WPB_SHORTS (3 * 6 * 8192)          // 294912 B (3 nb x 6 kc x 16KB tiles)
#define MB_TILES 1568                      // 4096*49/128 — exact
#define AV_BYTES ((size_t)MB_TILES * 6 * 16384)   // 154140672 B

__device__ __forceinline__ short f2bf(float f) {
    __bf16 h = (__bf16)f;
    return __builtin_bit_cast(short, h);
}
__device__ __forceinline__ float bf2f(short s) {
    u32 u = ((u32)(unsigned short)s) << 16;
    return __builtin_bit_cast(float, u);
}
__device__ __forceinline__ int cof(int p) { return 13 * (p / 7) + (p % 7); }

__device__ __forceinline__ void gld_lds16(const void* g, void* l) {
    __builtin_amdgcn_global_load_lds(
        (const __attribute__((address_space(1))) u32*)g,
        (__attribute__((address_space(3))) u32*)l, 16, 0, 0);
}

// fallback gather (fp32 source, uncoalesced — correctness path only)
__device__ __forceinline__ short8 gather_bf(const float* __restrict__ w, int row, int k0) {
    const float* p = w + row * DIMC + k0;
    float4 a = *(const float4*)p;
    float4 b = *(const float4*)(p + 4);
    short8 r;
    r[0]=f2bf(a.x); r[1]=f2bf(a.y); r[2]=f2bf(a.z); r[3]=f2bf(a.w);
    r[4]=f2bf(b.x); r[5]=f2bf(b.y); r[6]=f2bf(b.z); r[7]=f2bf(b.w);
    return r;
}

// -------- prep: fragment-tiled bf16 qkv weights + blocked-swizzled proj weights --------
__global__ void prep_weights(const float* __restrict__ qw, const float* __restrict__ pw,
                             short* __restrict__ wqb, short* __restrict__ wpb) {
    int gt = blockIdx.x * blockDim.x + threadIdx.x;
    if (gt < NQFRAG * 64) {
        int F = gt >> 6, lane = gt & 63;
        int h = F / 72, r = F % 72;
        int nt = r / 12, ks = r % 12;
        int l15 = lane & 15, l4 = lane >> 4;
        int grow = (nt >> 1) * DIMC + h * 32 + (nt & 1) * 16 + l15;
        const float* src = qw + grow * DIMC + ks * 32 + l4 * 8;
        short8 o;
        #pragma unroll
        for (int e = 0; e < 8; ++e) o[e] = f2bf(src[e]);
        *(short8*)(wqb + gt * 8) = o;
    } else if (gt < NQFRAG * 64 + 3 * 6 * 128 * 8) {
        int t2 = gt - NQFRAG * 64;        // [0, 18432)
        int g  = t2 & 7;                  // 16B group in row
        int r  = (t2 >> 3) & 127;         // row (= n within tile)
        int kc = (t2 >> 10) % 6;
        int nb = t2 / 6144;
        int k0 = kc * 64 + ((g ^ (r & 7)) << 3);
        const float* src = pw + (nb * 128 + r) * DIMC + k0;
        short8 o;
        #pragma unroll
        for (int e = 0; e < 8; ++e) o[e] = f2bf(src[e]);
        *(short8*)(wpb + (nb * 6 + kc) * 8192 + r * 64 + g * 8) = o;
    }
}

// ========== fused qkv + attention, 2 windows/block, counted-vmcnt pipeline ==========
__global__ __launch_bounds__(256, 2)
void winattn_fused(const float* __restrict__ x, const float* __restrict__ mask,
                   const float* __restrict__ qkv_b, const float* __restrict__ bias_table,
                   const short* __restrict__ wqb, char* __restrict__ avb)
{
    __shared__ short SL[SL_TOT] __attribute__((aligned(128)));

    const int tid  = threadIdx.x;
    const int wv   = tid >> 6;
    const int lane = tid & 63;
    const int l15  = lane & 15;
    const int l4   = lane >> 4;
    const int win0 = blockIdx.x * 2;

    // ---- stage bias_table + qkv_b to LDS (bf16) ----
    for (int i = tid; i < 169 * NH; i += 256) SL[BT_OFF + i] = f2bf(bias_table[i]);
    for (int i = tid; i < 3 * DIMC; i += 256) SL[QB_OFF + i] = f2bf(qkv_b[i]);

    // ---- x A-fragments in registers: 2 stripes x 12 k-steps ----
    short8 xf0[12], xf1[12];
    {
        const int row = wv * 16 + l15;
        const bool valid = row < NTOK;
        #pragma unroll
        for (int st = 0; st < 2; ++st) {
            const float* xr = x + (size_t)(win0 + st) * (NTOK * DIMC) + row * DIMC;
            #pragma unroll
            for (int ks = 0; ks < 12; ++ks) {
                short8 r;
                if (valid) {
                    float4 a = *(const float4*)(xr + ks * 32 + l4 * 8);
                    float4 b = *(const float4*)(xr + ks * 32 + l4 * 8 + 4);
                    r[0]=f2bf(a.x); r[1]=f2bf(a.y); r[2]=f2bf(a.z); r[3]=f2bf(a.w);
                    r[4]=f2bf(b.x); r[5]=f2bf(b.y); r[6]=f2bf(b.z); r[7]=f2bf(b.w);
                } else {
                    r = (short8)0;
                }
                if (st == 0) xf0[ks] = r; else xf1[ks] = r;
            }
        }
    }

    // ---- mask preload, packed bf16 pairs, col-pad -1e30 folded; rel-idx ----
    u32 mvp[2][4][2];
    int bidx[4][4];
    {
        #pragma unroll
        for (int st = 0; st < 2; ++st) {
            const float* maskp = mask + (size_t)((win0 + st) & 63) * (NTOK * NTOK);
            #pragma unroll
            for (int t = 0; t < 4; ++t) {
                int m = t * 16 + l15;
                float pad = (m < NTOK) ? 0.f : -1e30f;
                #pragma unroll
                for (int rp = 0; rp < 2; ++rp) {
                    float v[2];
                    #pragma unroll
                    for (int e = 0; e < 2; ++e) {
                        int i = wv * 16 + l4 * 4 + rp * 2 + e;
                        v[e] = ((i < NTOK && m < NTOK) ? maskp[i * NTOK + m] : 0.f) + pad;
                    }
                    mvp[st][t][rp] = (u32)(unsigned short)f2bf(v[0]) |
                                     ((u32)(unsigned short)f2bf(v[1]) << 16);
                }
            }
        }
        int cofi[4], cofm[4];
        #pragma unroll
        for (int t = 0; t < 4; ++t) {
            int m = t * 16 + l15;
            cofm[t] = cof(48 - (m < NTOK ? m : 48));
        }
        #pragma unroll
        for (int reg = 0; reg < 4; ++reg) {
            int i = wv * 16 + l4 * 4 + reg;
            cofi[reg] = cof(i < NTOK ? i : 48);
        }
        #pragma unroll
        for (int t = 0; t < 4; ++t)
            #pragma unroll
            for (int reg = 0; reg < 4; ++reg)
                bidx[t][reg] = (cofi[reg] + cofm[t]) * NH;
    }

    const f32x4 zf = (f32x4){0.f, 0.f, 0.f, 0.f};

    __syncthreads();   // BT/QB visible

    // prologue: issue chunks cg=0,1 into bufs 0,1
    #pragma unroll
    for (int pc = 0; pc < 2; ++pc) {
        #pragma unroll
        for (int t = 0; t < 3; ++t) {
            int jf = wv * 3 + t;
            int F = (jf >> 1) * 12 + 2 * pc + (jf & 1);
            gld_lds16(wqb + F * 512 + lane * 8, &SL[STG_OFF + pc * 6144 + jf * 512]);
        }
    }

    #pragma unroll 1
    for (int h = 0; h < NH; ++h) {
        // ================= qkv GEMM: 6 chunks, depth-2 counted pipeline =================
        f32x4 qa[12];
        #pragma unroll
        for (int t = 0; t < 12; ++t) qa[t] = zf;

        #pragma unroll
        for (int c = 0; c < 6; ++c) {
            asm volatile("s_waitcnt vmcnt(3)" ::: "memory");
            __builtin_amdgcn_s_barrier();
            __builtin_amdgcn_sched_barrier(0);
            // prefetch chunk cg+2 (wrapped) into buf (c+2)%3
            {
                int cg2 = h * 6 + c + 2;
                if (cg2 >= 72) cg2 -= 72;
                int hh = cg2 / 6, cc = cg2 - hh * 6;
                #pragma unroll
                for (int t = 0; t < 3; ++t) {
                    int jf = wv * 3 + t;
                    int F = (hh * 6 + (jf >> 1)) * 12 + 2 * cc + (jf & 1);
                    gld_lds16(wqb + F * 512 + lane * 8,
                              &SL[STG_OFF + ((c + 2) % 3) * 6144 + jf * 512]);
                }
            }
            __builtin_amdgcn_sched_barrier(0);
            const short* buf = &SL[STG_OFF + (c % 3) * 6144];
            __builtin_amdgcn_s_setprio(1);
            #pragma unroll
            for (int j = 0; j < 12; ++j) {
                short8 b = *(const short8*)(buf + j * 512 + lane * 8);
                const int nt = j >> 1, kk = 2 * c + (j & 1);
                qa[nt]     = __builtin_amdgcn_mfma_f32_16x16x32_bf16(xf0[kk], b, qa[nt], 0, 0, 0);
                qa[6 + nt] = __builtin_amdgcn_mfma_f32_16x16x32_bf16(xf1[kk], b, qa[6 + nt], 0, 0, 0);
            }
            __builtin_amdgcn_s_setprio(0);
        }

        // ===== epilogue: +bias, scale q; q->QA slab, k->KS[st], v->VT[st] =====
        #pragma unroll
        for (int st = 0; st < 2; ++st) {
            #pragma unroll
            for (int nt = 0; nt < 6; ++nt) {
                const int sub = nt >> 1;
                const int colw = (nt & 1) * 16 + l15;
                const float bias = bf2f(SL[QB_OFF + sub * DIMC + h * 32 + colw]);
                #pragma unroll
                for (int reg = 0; reg < 4; ++reg) {
                    const int rl = l4 * 4 + reg;        // row within stripe-wave (0..15)
                    const int tokg = wv * 16 + rl;      // token within window (0..63)
                    float val = qa[st * 6 + nt][reg] + bias;
                    if (sub == 0) {
                        int byt = rl * 64 + ((colw << 1) ^ ((rl & 3) << 4));
                        SL[QA_OFF + (wv * 2 + st) * 512 + (byt >> 1)] = f2bf(val * QSCALE);
                    } else if (sub == 1) {
                        int byt = tokg * 64 + ((colw << 1) ^ ((tokg & 3) << 4));
                        SL[KS_OFF + st * 2048 + (byt >> 1)] = f2bf(val);
                    } else {
                        int byt = colw * 128 + ((tokg << 1) ^ ((colw & 7) << 4));
                        SL[VT_OFF + st * 2048 + (byt >> 1)] = f2bf(val);
                    }
                }
            }
        }
        asm volatile("s_waitcnt lgkmcnt(0)" ::: "memory");
        __builtin_amdgcn_s_barrier();
        __builtin_amdgcn_sched_barrier(0);

        // ================= attention, per stripe =================
        #pragma unroll
        for (int st = 0; st < 2; ++st) {
            // QK^T
            short8 aq;
            {
                int byt = l15 * 64 + ((l4 * 16) ^ ((l15 & 3) << 4));
                aq = *(const short8*)&SL[QA_OFF + (wv * 2 + st) * 512 + (byt >> 1)];
            }
            f32x4 sc[4];
            #pragma unroll
            for (int t = 0; t < 4; ++t) {
                int row = t * 16 + l15;
                int byt = row * 64 + ((l4 * 16) ^ ((row & 3) << 4));
                short8 bk = *(const short8*)&SL[KS_OFF + st * 2048 + (byt >> 1)];
                sc[t] = __builtin_amdgcn_mfma_f32_16x16x32_bf16(aq, bk, zf, 0, 0, 0);
            }
            // logits + rel-bias + packed mask (pad folded), softmax
            float p[4][4];
            #pragma unroll
            for (int t = 0; t < 4; ++t) {
                #pragma unroll
                for (int reg = 0; reg < 4; ++reg) {
                    u32 pk = mvp[st][t][reg >> 1];
                    float mval = bf2f((short)((reg & 1) ? (pk >> 16) : (pk & 0xffff)));
                    float bt = bf2f(SL[BT_OFF + bidx[t][reg] + h]);
                    p[t][reg] = sc[t][reg] + mval + bt;
                }
            }
            #pragma unroll
            for (int reg = 0; reg < 4; ++reg) {
                float mx = fmaxf(fmaxf(p[0][reg], p[1][reg]), fmaxf(p[2][reg], p[3][reg]));
                #pragma unroll
                for (int off = 8; off >= 1; off >>= 1) mx = fmaxf(mx, __shfl_xor(mx, off, 64));
                float s0 = 0.f;
                #pragma unroll
                for (int t = 0; t < 4; ++t) { p[t][reg] = __expf(p[t][reg] - mx); s0 += p[t][reg]; }
                #pragma unroll
                for (int off = 8; off >= 1; off >>= 1) s0 += __shfl_xor(s0, off, 64);
                float rs = 1.f / s0;
                #pragma unroll
                for (int t = 0; t < 4; ++t) p[t][reg] *= rs;
            }
            // P -> per-wave PS slab (bf16, swizzled 128B rows)
            #pragma unroll
            for (int t = 0; t < 4; ++t)
                #pragma unroll
                for (int reg = 0; reg < 4; ++reg) {
                    int r = l4 * 4 + reg;
                    int byt = r * 128 + ((((t * 16 + l15) << 1)) ^ ((r & 7) << 4));
                    SL[PS_OFF + wv * 1024 + (byt >> 1)] = f2bf(p[t][reg]);
                }
            // PV
            f32x4 av[2];
            av[0] = zf; av[1] = zf;
            #pragma unroll
            for (int kst = 0; kst < 2; ++kst) {
                short8 pa;
                {
                    int byt = l15 * 128 + (((kst * 64 + l4 * 16)) ^ ((l15 & 7) << 4));
                    pa = *(const short8*)&SL[PS_OFF + wv * 1024 + (byt >> 1)];
                }
                #pragma unroll
                for (int dt = 0; dt < 2; ++dt) {
                    int d = dt * 16 + l15;
                    int byt = d * 128 + (((kst * 64 + l4 * 16)) ^ ((d & 7) << 4));
                    short8 bv = *(const short8*)&SL[VT_OFF + st * 2048 + (byt >> 1)];
                    av[dt] = __builtin_amdgcn_mfma_f32_16x16x32_bf16(pa, bv, av[dt], 0, 0, 0);
                }
            }
            // AV -> ws (blocked-swizzled proj tile layout)
            #pragma unroll
            for (int dt = 0; dt < 2; ++dt)
                #pragma unroll
                for (int reg = 0; reg < 4; ++reg) {
                    int tok = wv * 16 + l4 * 4 + reg;
                    if (tok < NTOK) {
                        int gt = (win0 + st) * NTOK + tok;
                        int mb = gt >> 7, r = gt & 127;
                        int inner = ((((h & 1) << 6) | ((dt * 16 + l15) << 1))) ^ ((r & 7) << 4);
                        *(short*)(avb + (size_t)(mb * 6 + (h >> 1)) * 16384 + r * 128 + inner)
                            = f2bf(av[dt][reg]);
                    }
                }
        }
        // next head's chunk-0 barrier orders KS/VT/QA/PS reuse
    }
}

// ================= proj GEMM: out[200704,384] = AV @ projW^T + b =================
__global__ __launch_bounds__(256, 2)
void proj_gemm(const char* __restrict__ avb, const short* __restrict__ wpb,
               const float* __restrict__ proj_b, float* __restrict__ out)
{
    __shared__ char LC[2][32768] __attribute__((aligned(128)));

    const int tid = threadIdx.x;
    const int wv = tid >> 6, lane = tid & 63;
    const int l15 = lane & 15, l4 = lane >> 4;
    const int wr = wv >> 1, wc = wv & 1;
    const int mb = blockIdx.x / 3, nb = blockIdx.x % 3;

    const char* asrc = avb + (size_t)mb * 6 * 16384;
    const char* bsrc = (const char*)wpb + (size_t)nb * 6 * 16384;

    f32x4 acc[4][4];
    #pragma unroll
    for (int mi = 0; mi < 4; ++mi)
        #pragma unroll
        for (int ni = 0; ni < 4; ++ni) acc[mi][ni] = (f32x4){0.f, 0.f, 0.f, 0.f};

    // prologue stage kc=0 into buf 0
    #pragma unroll
    for (int it = 0; it < 4; ++it) {
        int L = (wv * 4 + it) * 1024;
        gld_lds16(asrc + L + lane * 16, &LC[0][L]);
        gld_lds16(bsrc + L + lane * 16, &LC[0][16384 + L]);
    }

    #pragma unroll
    for (int kc = 0; kc < 6; ++kc) {
        __builtin_amdgcn_sched_barrier(0);
        asm volatile("s_waitcnt vmcnt(0)" ::: "memory");
        __builtin_amdgcn_s_barrier();
        __builtin_amdgcn_sched_barrier(0);
        if (kc < 5) {
            #pragma unroll
            for (int it = 0; it < 4; ++it) {
                int L = (wv * 4 + it) * 1024;
                gld_lds16(asrc + (kc + 1) * 16384 + L + lane * 16, &LC[(kc + 1) & 1][L]);
                gld_lds16(bsrc + (kc + 1) * 16384 + L + lane * 16, &LC[(kc + 1) & 1][16384 + L]);
            }
        }
        const char* bufp = LC[kc & 1];
        __builtin_amdgcn_s_setprio(1);
        #pragma unroll
        for (int ksub = 0; ksub < 2; ++ksub) {
            short8 a[4], b[4];
            #pragma unroll
            for (int mi = 0; mi < 4; ++mi) {
                int row = wr * 64 + mi * 16 + l15;
                a[mi] = *(const short8*)(bufp + row * 128 +
                        ((ksub * 64 + l4 * 16) ^ ((row & 7) << 4)));
            }
            #pragma unroll
            for (int ni = 0; ni < 4; ++ni) {
                int row = wc * 64 + ni * 16 + l15;
                b[ni] = *(const short8*)(bufp + 16384 + row * 128 +
                        ((ksub * 64 + l4 * 16) ^ ((row & 7) << 4)));
            }
            #pragma unroll
            for (int mi = 0; mi < 4; ++mi)
                #pragma unroll
                for (int ni = 0; ni < 4; ++ni)
                    acc[mi][ni] = __builtin_amdgcn_mfma_f32_16x16x32_bf16(
                        a[mi], b[ni], acc[mi][ni], 0, 0, 0);
        }
        __builtin_amdgcn_s_setprio(0);
    }

    // epilogue
    float pb[4];
    #pragma unroll
    for (int ni = 0; ni < 4; ++ni) pb[ni] = proj_b[nb * 128 + wc * 64 + ni * 16 + l15];
    #pragma unroll
    for (int mi = 0; mi < 4; ++mi) {
        #pragma unroll
        for (int ni = 0; ni < 4; ++ni) {
            #pragma unroll
            for (int reg = 0; reg < 4; ++reg) {
                size_t row = (size_t)(mb * 128 + wr * 64 + mi * 16 + l4 * 4 + reg);
                out[row * DIMC + nb * 128 + wc * 64 + ni * 16 + l15] = acc[mi][ni][reg] + pb[ni];
            }
        }
    }
}

// ================= fallback: monolithic gather kernel (no ws) =================
__global__ __launch_bounds__(256, 2)
void winattn_fallback(const float* __restrict__ x, const float* __restrict__ mask,
                      const float* __restrict__ qkv_w, const float* __restrict__ qkv_b,
                      const float* __restrict__ proj_w, const float* __restrict__ proj_b,
                      const float* __restrict__ bias_table, float* __restrict__ out)
{
    __shared__ short SL[26624] __attribute__((aligned(128)));
    // local layout: KS 0, VT 2048, PS 4096(->8192), QA 8192, rest scratch
    const int tid = threadIdx.x, wv = tid >> 6, lane = tid & 63;
    const int l15 = lane & 15, l4 = lane >> 4;
    const int win = blockIdx.x;
    const int xbase = win * (NTOK * DIMC);
    const int KSo = 0, VTo = 2048, PSo = 4096, QAo = 8192;

    short8 xf[12];
    {
        const int row = wv * 16 + l15;
        const bool valid = row < NTOK;
        const float* xr = x + xbase + row * DIMC;
        #pragma unroll
        for (int ks = 0; ks < 12; ++ks)
            xf[ks] = valid ? gather_bf(xr, 0, ks * 32 + l4 * 8) : (short8)0;
    }
    float mv[4][4]; int bidx[4][4]; float negm[4];
    {
        const float* maskp = mask + (win & 63) * (NTOK * NTOK);
        int cofi[4], cofm[4];
        #pragma unroll
        for (int t = 0; t < 4; ++t) {
            int m = t * 16 + l15;
            negm[t] = (m < NTOK) ? 0.f : -1e30f;
            cofm[t] = cof(48 - (m < NTOK ? m : 48));
            #pragma unroll
            for (int reg = 0; reg < 4; ++reg) {
                int i = wv * 16 + l4 * 4 + reg;
                mv[t][reg] = (i < NTOK && m < NTOK) ? maskp[i * NTOK + m] : 0.f;
            }
        }
        #pragma unroll
        for (int reg = 0; reg < 4; ++reg) {
            int i = wv * 16 + l4 * 4 + reg;
            cofi[reg] = cof(i < NTOK ? i : 48);
        }
        #pragma unroll
        for (int t = 0; t < 4; ++t)
            #pragma unroll
            for (int reg = 0; reg < 4; ++reg) bidx[t][reg] = (cofi[reg] + cofm[t]) * NH;
    }
    f32x4 pacc[24];
    #pragma unroll
    for (int t = 0; t < 24; ++t) pacc[t] = (f32x4){0.f, 0.f, 0.f, 0.f};
    const f32x4 zf = (f32x4){0.f, 0.f, 0.f, 0.f};
    __syncthreads();

    #pragma unroll 1
    for (int h = 0; h < NH; ++h) {
        f32x4 qa[6];
        #pragma unroll
        for (int nt = 0; nt < 6; ++nt) qa[nt] = zf;
        #pragma unroll
        for (int nt = 0; nt < 6; ++nt) {
            const int grow = (nt >> 1) * DIMC + h * 32 + (nt & 1) * 16 + l15;
            #pragma unroll
            for (int ks = 0; ks < 12; ++ks) {
                short8 b = gather_bf(qkv_w, grow, ks * 32 + l4 * 8);
                qa[nt] = __builtin_amdgcn_mfma_f32_16x16x32_bf16(xf[ks], b, qa[nt], 0, 0, 0);
            }
        }
        #pragma unroll
        for (int nt = 0; nt < 6; ++nt) {
            const int sub = nt >> 1;
            const int colw = (nt & 1) * 16 + l15;
            const float bias = qkv_b[sub * DIMC + h * 32 + colw];
            #pragma unroll
            for (int reg = 0; reg < 4; ++reg) {
                const int tokg = wv * 16 + l4 * 4 + reg;
                float val = qa[nt][reg] + bias;
                if (sub == 0) {
                    int byt = tokg * 64 + ((colw << 1) ^ ((tokg & 3) << 4));
                    SL[QAo + (byt >> 1)] = f2bf(val * QSCALE);
                } else if (sub == 1) {
                    int byt = tokg * 64 + ((colw << 1) ^ ((tokg & 3) << 4));
                    SL[KSo + (byt >> 1)] = f2bf(val);
                } else {
                    int byt = colw * 128 + ((tokg << 1) ^ ((colw & 7) << 4));
                    SL[VTo + (byt >> 1)] = f2bf(val);
                }
            }
        }
        __syncthreads();
        short8 aq;
        { int row = wv*16+l15; int byt = row*64 + ((l4*16) ^ ((row&3)<<4));
          aq = *(const short8*)&SL[QAo + (byt>>1)]; }
        f32x4 sc[4];
        #pragma unroll
        for (int t = 0; t < 4; ++t) {
            int row = t*16+l15; int byt = row*64 + ((l4*16) ^ ((row&3)<<4));
            short8 bk = *(const short8*)&SL[KSo + (byt>>1)];
            sc[t] = __builtin_amdgcn_mfma_f32_16x16x32_bf16(aq, bk, zf, 0, 0, 0);
        }
        float p[4][4];
        #pragma unroll
        for (int t = 0; t < 4; ++t)
            #pragma unroll
            for (int reg = 0; reg < 4; ++reg)
                p[t][reg] = sc[t][reg] + mv[t][reg] + bias_table[bidx[t][reg] + h] + negm[t];
        #pragma unroll
        for (int reg = 0; reg < 4; ++reg) {
            float mx = fmaxf(fmaxf(p[0][reg], p[1][reg]), fmaxf(p[2][reg], p[3][reg]));
            #pragma unroll
            for (int off = 8; off >= 1; off >>= 1) mx = fmaxf(mx, __shfl_xor(mx, off, 64));
            float s0 = 0.f;
            #pragma unroll
            for (int t = 0; t < 4; ++t) { p[t][reg] = __expf(p[t][reg] - mx); s0 += p[t][reg]; }
            #pragma unroll
            for (int off = 8; off >= 1; off >>= 1) s0 += __shfl_xor(s0, off, 64);
            float rs = 1.f / s0;
            #pragma unroll
            for (int t = 0; t < 4; ++t) p[t][reg] *= rs;
        }
        #pragma unroll
        for (int t = 0; t < 4; ++t)
            #pragma unroll
            for (int reg = 0; reg < 4; ++reg) {
                int row = wv*16 + l4*4 + reg;
                int byt = row*128 + (((t*16+l15) << 1) ^ ((row&7)<<4));
                SL[PSo + (byt>>1)] = f2bf(p[t][reg]);
            }
        f32x4 av[2]; av[0] = zf; av[1] = zf;
        #pragma unroll
        for (int kst = 0; kst < 2; ++kst) {
            short8 pa;
            { int row = wv*16+l15; int byt = row*128 + ((kst*64+l4*16) ^ ((row&7)<<4));
              pa = *(const short8*)&SL[PSo + (byt>>1)]; }
            #pragma unroll
            for (int dt = 0; dt < 2; ++dt) {
                int d = dt*16+l15; int byt = d*128 + ((kst*64+l4*16) ^ ((d&7)<<4));
                short8 bv = *(const short8*)&SL[VTo + (byt>>1)];
                av[dt] = __builtin_amdgcn_mfma_f32_16x16x32_bf16(pa, bv, av[dt], 0, 0, 0);
            }
        }
        __syncthreads();
        #pragma unroll
        for (int dt = 0; dt < 2; ++dt)
            #pragma unroll
            for (int reg = 0; reg < 4; ++reg) {
                int row = wv*16 + l4*4 + reg;
                int byt = row*64 + (((dt*16+l15) << 1) ^ ((row&3)<<4));
                SL[QAo + (byt>>1)] = f2bf(av[dt][reg]);
            }
        __syncthreads();
        short8 aa;
        { int row = wv*16+l15; int byt = row*64 + ((l4*16) ^ ((row&3)<<4));
          aa = *(const short8*)&SL[QAo + (byt>>1)]; }
        #pragma unroll
        for (int nt = 0; nt < 24; ++nt) {
            short8 bp = gather_bf(proj_w, nt * 16 + l15, h * 32 + l4 * 8);
            pacc[nt] = __builtin_amdgcn_mfma_f32_16x16x32_bf16(aa, bp, pacc[nt], 0, 0, 0);
        }
    }
    {
        float* op = out + xbase;
        #pragma unroll
        for (int nt = 0; nt < 24; ++nt) {
            const float pb = proj_b[nt * 16 + l15];
            #pragma unroll
            for (int reg = 0; reg < 4; ++reg) {
                const int i = wv * 16 + l4 * 4 + reg;
                if (i < NTOK) op[i * DIMC + nt * 16 + l15] = pacc[nt][reg] + pb;
            }
        }
    }
}

extern "C" void kernel_launch(void* const* d_in, const int* in_sizes, int n_in,
                              void* d_out, int out_size, void* d_ws, size_t ws_size,
                              hipStream_t stream) {
    const float* x          = (const float*)d_in[0];
    const float* mask       = (const float*)d_in[1];
    const float* qkv_w      = (const float*)d_in[2];
    const float* qkv_b      = (const float*)d_in[3];
    const float* proj_w     = (const float*)d_in[4];
    const float* proj_b     = (const float*)d_in[5];
    const float* bias_table = (const float*)d_in[6];
    float* out = (float*)d_out;

    const size_t need = (size_t)WQB_SHORTS * 2 + (size_t)WPB_SHORTS * 2 + AV_BYTES;
    if (ws_size >= need) {
        short* wqb = (short*)d_ws;
        short* wpb = wqb + WQB_SHORTS;
        char*  avb = (char*)(wpb + WPB_SHORTS);
        prep_weights<<<288, 256, 0, stream>>>(qkv_w, proj_w, wqb, wpb);
        winattn_fused<<<2048, 256, 0, stream>>>(x, mask, qkv_b, bias_table, wqb, avb);
        proj_gemm<<<MB_TILES * 3, 256, 0, stream>>>(avb, wpb, proj_b, out);
    } else {
        winattn_fallback<<<4096, 256, 0, stream>>>(x, mask, qkv_w, qkv_b, proj_w,
                                                   proj_b, bias_table, out);
    }
}

// Round 8
// 869.375 us; speedup vs baseline: 1.0023x; 1.0023x over previous
//
#include <hip/hip_runtime.h>
#include <hip/hip_bf16.h>

#define NTOK 49
#define DIMC 384
#define NH 12
#define QSCALE 0.17677669529663687f

typedef __attribute__((ext_vector_type(8))) short short8;
typedef __attribute__((ext_vector_type(4))) float f32x4;
typedef unsigned int u32;

// ---------------- LDS layout for fused kernel (short units) ----------------
// KS: 2 parity x [64 tok][64 sh] 128B rows swz = 8192
// VT: 2 parity x [32 dim][64 tok] 128B rows swz = 4096
// PS: 4 waves x [16][64] 128B rows swz          = 4096
// QA: 4 waves x [16][32] 64B rows swz           = 2048
// BT: 2028->2032 ; QB: 1152  => 21616 sh = 43232 B
#define KS_OFF  0
#define VT_OFF  8192
#define PS_OFF  12288
#define QA_OFF  16384
#define BT_OFF  18432
#define QB_OFF  20464
#define SL_TOT  21616

#define NQFRAG (NH * 6 * 12)               // 864 qkv fragments
#define WQB_SHORTS (NQFRAG * 512)          // 884736 B
#define WPB_SHORTS (3 * 6 * 8192)          // 294912 B (3 nb x 6 kc x 16KB tiles)
#define MB_TILES 1568                      // 4096*49/128 — exact
#define AV_BYTES ((size_t)MB_TILES * 6 * 16384)   // 154140672 B

__device__ __forceinline__ short f2bf(float f) {
    __bf16 h = (__bf16)f;
    return __builtin_bit_cast(short, h);
}
__device__ __forceinline__ float bf2f(short s) {
    u32 u = ((u32)(unsigned short)s) << 16;
    return __builtin_bit_cast(float, u);
}
__device__ __forceinline__ int cof(int p) { return 13 * (p / 7) + (p % 7); }

__device__ __forceinline__ void gld_lds16(const void* g, void* l) {
    __builtin_amdgcn_global_load_lds(
        (const __attribute__((address_space(1))) u32*)g,
        (__attribute__((address_space(3))) u32*)l, 16, 0, 0);
}

// fallback gather (fp32 source, uncoalesced — correctness path only)
__device__ __forceinline__ short8 gather_bf(const float* __restrict__ w, int row, int k0) {
    const float* p = w + row * DIMC + k0;
    float4 a = *(const float4*)p;
    float4 b = *(const float4*)(p + 4);
    short8 r;
    r[0]=f2bf(a.x); r[1]=f2bf(a.y); r[2]=f2bf(a.z); r[3]=f2bf(a.w);
    r[4]=f2bf(b.x); r[5]=f2bf(b.y); r[6]=f2bf(b.z); r[7]=f2bf(b.w);
    return r;
}

// -------- prep: fragment-tiled bf16 qkv weights + blocked-swizzled proj weights --------
__global__ void prep_weights(const float* __restrict__ qw, const float* __restrict__ pw,
                             short* __restrict__ wqb, short* __restrict__ wpb) {
    int gt = blockIdx.x * blockDim.x + threadIdx.x;
    if (gt < NQFRAG * 64) {
        int F = gt >> 6, lane = gt & 63;
        int h = F / 72, r = F % 72;
        int nt = r / 12, ks = r % 12;
        int l15 = lane & 15, l4 = lane >> 4;
        int grow = (nt >> 1) * DIMC + h * 32 + (nt & 1) * 16 + l15;
        const float* src = qw + grow * DIMC + ks * 32 + l4 * 8;
        short8 o;
        #pragma unroll
        for (int e = 0; e < 8; ++e) o[e] = f2bf(src[e]);
        *(short8*)(wqb + gt * 8) = o;
    } else if (gt < NQFRAG * 64 + 3 * 6 * 128 * 8) {
        int t2 = gt - NQFRAG * 64;        // [0, 18432)
        int g  = t2 & 7;                  // 16B group in row
        int r  = (t2 >> 3) & 127;         // row (= n within tile)
        int kc = (t2 >> 10) % 6;
        int nb = t2 / 6144;
        int k0 = kc * 64 + ((g ^ (r & 7)) << 3);
        const float* src = pw + (nb * 128 + r) * DIMC + k0;
        short8 o;
        #pragma unroll
        for (int e = 0; e < 8; ++e) o[e] = f2bf(src[e]);
        *(short8*)(wpb + (nb * 6 + kc) * 8192 + r * 64 + g * 8) = o;
    }
}

// ========== fused qkv + attention: B-frags direct to registers, 1 barrier/head ==========
__global__ __launch_bounds__(256, 2)
void winattn_fused(const float* __restrict__ x, const float* __restrict__ mask,
                   const float* __restrict__ qkv_b, const float* __restrict__ bias_table,
                   const short* __restrict__ wqb, char* __restrict__ avb)
{
    __shared__ short SL[SL_TOT] __attribute__((aligned(128)));

    const int tid  = threadIdx.x;
    const int wv   = tid >> 6;
    const int lane = tid & 63;
    const int l15  = lane & 15;
    const int l4   = lane >> 4;
    const int win  = blockIdx.x;

    // ---- stage bias_table + qkv_b to LDS (bf16) ----
    for (int i = tid; i < 169 * NH; i += 256) SL[BT_OFF + i] = f2bf(bias_table[i]);
    for (int i = tid; i < 3 * DIMC; i += 256) SL[QB_OFF + i] = f2bf(qkv_b[i]);

    // ---- x A-fragments in registers: 12 k-steps x short8 ----
    short8 xf[12];
    {
        const int row = wv * 16 + l15;
        const bool valid = row < NTOK;
        const float* xr = x + (size_t)win * (NTOK * DIMC) + row * DIMC;
        #pragma unroll
        for (int ks = 0; ks < 12; ++ks) {
            short8 r;
            if (valid) {
                float4 a = *(const float4*)(xr + ks * 32 + l4 * 8);
                float4 b = *(const float4*)(xr + ks * 32 + l4 * 8 + 4);
                r[0]=f2bf(a.x); r[1]=f2bf(a.y); r[2]=f2bf(a.z); r[3]=f2bf(a.w);
                r[4]=f2bf(b.x); r[5]=f2bf(b.y); r[6]=f2bf(b.z); r[7]=f2bf(b.w);
            } else {
                r = (short8)0;
            }
            xf[ks] = r;
        }
    }

    // ---- mask preload (packed bf16 pairs, col-pad -1e30 folded) + rel-idx ----
    u32 mvp[4][2];
    int bidx[4][4];
    {
        const float* maskp = mask + (size_t)(win & 63) * (NTOK * NTOK);
        #pragma unroll
        for (int t = 0; t < 4; ++t) {
            int m = t * 16 + l15;
            float pad = (m < NTOK) ? 0.f : -1e30f;
            #pragma unroll
            for (int rp = 0; rp < 2; ++rp) {
                float v[2];
                #pragma unroll
                for (int e = 0; e < 2; ++e) {
                    int i = wv * 16 + l4 * 4 + rp * 2 + e;
                    v[e] = ((i < NTOK && m < NTOK) ? maskp[i * NTOK + m] : 0.f) + pad;
                }
                mvp[t][rp] = (u32)(unsigned short)f2bf(v[0]) |
                             ((u32)(unsigned short)f2bf(v[1]) << 16);
            }
        }
        int cofi[4], cofm[4];
        #pragma unroll
        for (int t = 0; t < 4; ++t) {
            int m = t * 16 + l15;
            cofm[t] = cof(48 - (m < NTOK ? m : 48));
        }
        #pragma unroll
        for (int reg = 0; reg < 4; ++reg) {
            int i = wv * 16 + l4 * 4 + reg;
            cofi[reg] = cof(i < NTOK ? i : 48);
        }
        #pragma unroll
        for (int t = 0; t < 4; ++t)
            #pragma unroll
            for (int reg = 0; reg < 4; ++reg)
                bidx[t][reg] = (cofi[reg] + cofm[t]) * NH;
    }

    const f32x4 zf = (f32x4){0.f, 0.f, 0.f, 0.f};

    __syncthreads();   // BT/QB visible

    // ---- per-head qkv GEMM + epilogue (B-frags direct from global to regs) ----
    auto qkv_head = [&](int h) {
        const int p = h & 1;
        f32x4 qa[6];
        #pragma unroll
        for (int nt = 0; nt < 6; ++nt) qa[nt] = zf;
        const short* wq_h = wqb + (size_t)h * 36864 + lane * 8;
        #pragma unroll
        for (int c = 0; c < 6; ++c) {
            short8 bfr[12];
            #pragma unroll
            for (int j = 0; j < 12; ++j)
                bfr[j] = *(const short8*)(wq_h + (((j >> 1) * 12) + 2 * c + (j & 1)) * 512);
            #pragma unroll
            for (int j = 0; j < 12; ++j)
                qa[j >> 1] = __builtin_amdgcn_mfma_f32_16x16x32_bf16(
                    xf[2 * c + (j & 1)], bfr[j], qa[j >> 1], 0, 0, 0);
        }
        // epilogue: +bias, scale q; q->QA(wave), k->KS[p], v->VT[p]
        #pragma unroll
        for (int nt = 0; nt < 6; ++nt) {
            const int sub = nt >> 1;
            const int colw = (nt & 1) * 16 + l15;
            const float bias = bf2f(SL[QB_OFF + sub * DIMC + h * 32 + colw]);
            #pragma unroll
            for (int reg = 0; reg < 4; ++reg) {
                const int rl = l4 * 4 + reg;
                const int tokg = wv * 16 + rl;
                float val = qa[nt][reg] + bias;
                if (sub == 0) {
                    int byt = rl * 64 + ((colw << 1) ^ ((rl & 3) << 4));
                    SL[QA_OFF + wv * 512 + (byt >> 1)] = f2bf(val * QSCALE);
                } else if (sub == 1) {
                    int byt = tokg * 128 + ((colw << 1) ^ ((tokg & 7) << 4));
                    SL[KS_OFF + p * 4096 + (byt >> 1)] = f2bf(val);
                } else {
                    int byt = colw * 128 + ((tokg << 1) ^ ((colw & 7) << 4));
                    SL[VT_OFF + p * 2048 + (byt >> 1)] = f2bf(val);
                }
            }
        }
        asm volatile("s_waitcnt lgkmcnt(0)" ::: "memory");
        __builtin_amdgcn_s_barrier();
        __builtin_amdgcn_sched_barrier(0);
    };

    // ---- attention for head hh (reads KS/VT[hh&1], QA/PS wave slabs) ----
    auto attn_head = [&](int hh) {
        const int pp = hh & 1;
        short8 aq;
        {
            int byt = l15 * 64 + ((l4 * 16) ^ ((l15 & 3) << 4));
            aq = *(const short8*)&SL[QA_OFF + wv * 512 + (byt >> 1)];
        }
        f32x4 sc[4];
        #pragma unroll
        for (int t = 0; t < 4; ++t) {
            int row = t * 16 + l15;
            int byt = row * 128 + ((l4 * 16) ^ ((row & 7) << 4));
            short8 bk = *(const short8*)&SL[KS_OFF + pp * 4096 + (byt >> 1)];
            sc[t] = __builtin_amdgcn_mfma_f32_16x16x32_bf16(aq, bk, zf, 0, 0, 0);
        }
        float p[4][4];
        #pragma unroll
        for (int t = 0; t < 4; ++t) {
            #pragma unroll
            for (int reg = 0; reg < 4; ++reg) {
                u32 pk = mvp[t][reg >> 1];
                float mval = bf2f((short)((reg & 1) ? (pk >> 16) : (pk & 0xffff)));
                float bt = bf2f(SL[BT_OFF + bidx[t][reg] + hh]);
                p[t][reg] = sc[t][reg] + mval + bt;
            }
        }
        #pragma unroll
        for (int reg = 0; reg < 4; ++reg) {
            float mx = fmaxf(fmaxf(p[0][reg], p[1][reg]), fmaxf(p[2][reg], p[3][reg]));
            #pragma unroll
            for (int off = 8; off >= 1; off >>= 1) mx = fmaxf(mx, __shfl_xor(mx, off, 64));
            float s0 = 0.f;
            #pragma unroll
            for (int t = 0; t < 4; ++t) { p[t][reg] = __expf(p[t][reg] - mx); s0 += p[t][reg]; }
            #pragma unroll
            for (int off = 8; off >= 1; off >>= 1) s0 += __shfl_xor(s0, off, 64);
            float rs = 1.f / s0;
            #pragma unroll
            for (int t = 0; t < 4; ++t) p[t][reg] *= rs;
        }
        // P -> per-wave PS slab (bf16, swizzled 128B rows)
        #pragma unroll
        for (int t = 0; t < 4; ++t)
            #pragma unroll
            for (int reg = 0; reg < 4; ++reg) {
                int r = l4 * 4 + reg;
                int byt = r * 128 + ((((t * 16 + l15) << 1)) ^ ((r & 7) << 4));
                SL[PS_OFF + wv * 1024 + (byt >> 1)] = f2bf(p[t][reg]);
            }
        // PV
        f32x4 av[2];
        av[0] = zf; av[1] = zf;
        #pragma unroll
        for (int kst = 0; kst < 2; ++kst) {
            short8 pa;
            {
                int byt = l15 * 128 + (((kst * 64 + l4 * 16)) ^ ((l15 & 7) << 4));
                pa = *(const short8*)&SL[PS_OFF + wv * 1024 + (byt >> 1)];
            }
            #pragma unroll
            for (int dt = 0; dt < 2; ++dt) {
                int d = dt * 16 + l15;
                int byt = d * 128 + (((kst * 64 + l4 * 16)) ^ ((d & 7) << 4));
                short8 bv = *(const short8*)&SL[VT_OFF + pp * 2048 + (byt >> 1)];
                av[dt] = __builtin_amdgcn_mfma_f32_16x16x32_bf16(pa, bv, av[dt], 0, 0, 0);
            }
        }
        // AV -> ws (blocked-swizzled proj tile layout)
        #pragma unroll
        for (int dt = 0; dt < 2; ++dt)
            #pragma unroll
            for (int reg = 0; reg < 4; ++reg) {
                int tok = wv * 16 + l4 * 4 + reg;
                if (tok < NTOK) {
                    int gt = win * NTOK + tok;
                    int mb = gt >> 7, r = gt & 127;
                    int inner = ((((hh & 1) << 6) | ((dt * 16 + l15) << 1))) ^ ((r & 7) << 4);
                    *(short*)(avb + (size_t)(mb * 6 + (hh >> 1)) * 16384 + r * 128 + inner)
                        = f2bf(av[dt][reg]);
                }
            }
    };

    // software-pipelined: region h = [attn(h-1) ||| qkv(h)+epi(h)] between barriers
    qkv_head(0);
    #pragma unroll 1
    for (int h = 1; h < NH; ++h) {
        attn_head(h - 1);
        qkv_head(h);
    }
    attn_head(NH - 1);
}

// ================= proj GEMM: out[200704,384] = AV @ projW^T + b =================
__global__ __launch_bounds__(256, 2)
void proj_gemm(const char* __restrict__ avb, const short* __restrict__ wpb,
               const float* __restrict__ proj_b, float* __restrict__ out)
{
    __shared__ char LC[2][32768] __attribute__((aligned(128)));

    const int tid = threadIdx.x;
    const int wv = tid >> 6, lane = tid & 63;
    const int l15 = lane & 15, l4 = lane >> 4;
    const int wr = wv >> 1, wc = wv & 1;
    const int mb = blockIdx.x / 3, nb = blockIdx.x % 3;

    const char* asrc = avb + (size_t)mb * 6 * 16384;
    const char* bsrc = (const char*)wpb + (size_t)nb * 6 * 16384;

    f32x4 acc[4][4];
    #pragma unroll
    for (int mi = 0; mi < 4; ++mi)
        #pragma unroll
        for (int ni = 0; ni < 4; ++ni) acc[mi][ni] = (f32x4){0.f, 0.f, 0.f, 0.f};

    // prologue stage kc=0 into buf 0
    #pragma unroll
    for (int it = 0; it < 4; ++it) {
        int L = (wv * 4 + it) * 1024;
        gld_lds16(asrc + L + lane * 16, &LC[0][L]);
        gld_lds16(bsrc + L + lane * 16, &LC[0][16384 + L]);
    }

    #pragma unroll
    for (int kc = 0; kc < 6; ++kc) {
        __builtin_amdgcn_sched_barrier(0);
        asm volatile("s_waitcnt vmcnt(0)" ::: "memory");
        __builtin_amdgcn_s_barrier();
        __builtin_amdgcn_sched_barrier(0);
        if (kc < 5) {
            #pragma unroll
            for (int it = 0; it < 4; ++it) {
                int L = (wv * 4 + it) * 1024;
                gld_lds16(asrc + (kc + 1) * 16384 + L + lane * 16, &LC[(kc + 1) & 1][L]);
                gld_lds16(bsrc + (kc + 1) * 16384 + L + lane * 16, &LC[(kc + 1) & 1][16384 + L]);
            }
        }
        const char* bufp = LC[kc & 1];
        __builtin_amdgcn_s_setprio(1);
        #pragma unroll
        for (int ksub = 0; ksub < 2; ++ksub) {
            short8 a[4], b[4];
            #pragma unroll
            for (int mi = 0; mi < 4; ++mi) {
                int row = wr * 64 + mi * 16 + l15;
                a[mi] = *(const short8*)(bufp + row * 128 +
                        ((ksub * 64 + l4 * 16) ^ ((row & 7) << 4)));
            }
            #pragma unroll
            for (int ni = 0; ni < 4; ++ni) {
                int row = wc * 64 + ni * 16 + l15;
                b[ni] = *(const short8*)(bufp + 16384 + row * 128 +
                        ((ksub * 64 + l4 * 16) ^ ((row & 7) << 4)));
            }
            #pragma unroll
            for (int mi = 0; mi < 4; ++mi)
                #pragma unroll
                for (int ni = 0; ni < 4; ++ni)
                    acc[mi][ni] = __builtin_amdgcn_mfma_f32_16x16x32_bf16(
                        a[mi], b[ni], acc[mi][ni], 0, 0, 0);
        }
        __builtin_amdgcn_s_setprio(0);
    }

    // epilogue
    float pb[4];
    #pragma unroll
    for (int ni = 0; ni < 4; ++ni) pb[ni] = proj_b[nb * 128 + wc * 64 + ni * 16 + l15];
    #pragma unroll
    for (int mi = 0; mi < 4; ++mi) {
        #pragma unroll
        for (int ni = 0; ni < 4; ++ni) {
            #pragma unroll
            for (int reg = 0; reg < 4; ++reg) {
                size_t row = (size_t)(mb * 128 + wr * 64 + mi * 16 + l4 * 4 + reg);
                out[row * DIMC + nb * 128 + wc * 64 + ni * 16 + l15] = acc[mi][ni][reg] + pb[ni];
            }
        }
    }
}

// ================= fallback: monolithic gather kernel (no ws) =================
__global__ __launch_bounds__(256, 2)
void winattn_fallback(const float* __restrict__ x, const float* __restrict__ mask,
                      const float* __restrict__ qkv_w, const float* __restrict__ qkv_b,
                      const float* __restrict__ proj_w, const float* __restrict__ proj_b,
                      const float* __restrict__ bias_table, float* __restrict__ out)
{
    __shared__ short SL[26624] __attribute__((aligned(128)));
    const int tid = threadIdx.x, wv = tid >> 6, lane = tid & 63;
    const int l15 = lane & 15, l4 = lane >> 4;
    const int win = blockIdx.x;
    const int xbase = win * (NTOK * DIMC);
    const int KSo = 0, VTo = 2048, PSo = 4096, QAo = 8192;

    short8 xf[12];
    {
        const int row = wv * 16 + l15;
        const bool valid = row < NTOK;
        const float* xr = x + xbase + row * DIMC;
        #pragma unroll
        for (int ks = 0; ks < 12; ++ks)
            xf[ks] = valid ? gather_bf(xr, 0, ks * 32 + l4 * 8) : (short8)0;
    }
    float mv[4][4]; int bidx[4][4]; float negm[4];
    {
        const float* maskp = mask + (win & 63) * (NTOK * NTOK);
        int cofi[4], cofm[4];
        #pragma unroll
        for (int t = 0; t < 4; ++t) {
            int m = t * 16 + l15;
            negm[t] = (m < NTOK) ? 0.f : -1e30f;
            cofm[t] = cof(48 - (m < NTOK ? m : 48));
            #pragma unroll
            for (int reg = 0; reg < 4; ++reg) {
                int i = wv * 16 + l4 * 4 + reg;
                mv[t][reg] = (i < NTOK && m < NTOK) ? maskp[i * NTOK + m] : 0.f;
            }
        }
        #pragma unroll
        for (int reg = 0; reg < 4; ++reg) {
            int i = wv * 16 + l4 * 4 + reg;
            cofi[reg] = cof(i < NTOK ? i : 48);
        }
        #pragma unroll
        for (int t = 0; t < 4; ++t)
            #pragma unroll
            for (int reg = 0; reg < 4; ++reg) bidx[t][reg] = (cofi[reg] + cofm[t]) * NH;
    }
    f32x4 pacc[24];
    #pragma unroll
    for (int t = 0; t < 24; ++t) pacc[t] = (f32x4){0.f, 0.f, 0.f, 0.f};
    const f32x4 zf = (f32x4){0.f, 0.f, 0.f, 0.f};
    __syncthreads();

    #pragma unroll 1
    for (int h = 0; h < NH; ++h) {
        f32x4 qa[6];
        #pragma unroll
        for (int nt = 0; nt < 6; ++nt) qa[nt] = zf;
        #pragma unroll
        for (int nt = 0; nt < 6; ++nt) {
            const int grow = (nt >> 1) * DIMC + h * 32 + (nt & 1) * 16 + l15;
            #pragma unroll
            for (int ks = 0; ks < 12; ++ks) {
                short8 b = gather_bf(qkv_w, grow, ks * 32 + l4 * 8);
                qa[nt] = __builtin_amdgcn_mfma_f32_16x16x32_bf16(xf[ks], b, qa[nt], 0, 0, 0);
            }
        }
        #pragma unroll
        for (int nt = 0; nt < 6; ++nt) {
            const int sub = nt >> 1;
            const int colw = (nt & 1) * 16 + l15;
            const float bias = qkv_b[sub * DIMC + h * 32 + colw];
            #pragma unroll
            for (int reg = 0; reg < 4; ++reg) {
                const int tokg = wv * 16 + l4 * 4 + reg;
                float val = qa[nt][reg] + bias;
                if (sub == 0) {
                    int byt = tokg * 64 + ((colw << 1) ^ ((tokg & 3) << 4));
                    SL[QAo + (byt >> 1)] = f2bf(val * QSCALE);
                } else if (sub == 1) {
                    int byt = tokg * 64 + ((colw << 1) ^ ((tokg & 3) << 4));
                    SL[KSo + (byt >> 1)] = f2bf(val);
                } else {
                    int byt = colw * 128 + ((tokg << 1) ^ ((colw & 7) << 4));
                    SL[VTo + (byt >> 1)] = f2bf(val);
                }
            }
        }
        __syncthreads();
        short8 aq;
        { int row = wv*16+l15; int byt = row*64 + ((l4*16) ^ ((row&3)<<4));
          aq = *(const short8*)&SL[QAo + (byt>>1)]; }
        f32x4 sc[4];
        #pragma unroll
        for (int t = 0; t < 4; ++t) {
            int row = t*16+l15; int byt = row*64 + ((l4*16) ^ ((row&3)<<4));
            short8 bk = *(const short8*)&SL[KSo + (byt>>1)];
            sc[t] = __builtin_amdgcn_mfma_f32_16x16x32_bf16(aq, bk, zf, 0, 0, 0);
        }
        float p[4][4];
        #pragma unroll
        for (int t = 0; t < 4; ++t)
            #pragma unroll
            for (int reg = 0; reg < 4; ++reg)
                p[t][reg] = sc[t][reg] + mv[t][reg] + bias_table[bidx[t][reg] + h] + negm[t];
        #pragma unroll
        for (int reg = 0; reg < 4; ++reg) {
            float mx = fmaxf(fmaxf(p[0][reg], p[1][reg]), fmaxf(p[2][reg], p[3][reg]));
            #pragma unroll
            for (int off = 8; off >= 1; off >>= 1) mx = fmaxf(mx, __shfl_xor(mx, off, 64));
            float s0 = 0.f;
            #pragma unroll
            for (int t = 0; t < 4; ++t) { p[t][reg] = __expf(p[t][reg] - mx); s0 += p[t][reg]; }
            #pragma unroll
            for (int off = 8; off >= 1; off >>= 1) s0 += __shfl_xor(s0, off, 64);
            float rs = 1.f / s0;
            #pragma unroll
            for (int t = 0; t < 4; ++t) p[t][reg] *= rs;
        }
        #pragma unroll
        for (int t = 0; t < 4; ++t)
            #pragma unroll
            for (int reg = 0; reg < 4; ++reg) {
                int row = wv*16 + l4*4 + reg;
                int byt = row*128 + (((t*16+l15) << 1) ^ ((row&7)<<4));
                SL[PSo + (byt>>1)] = f2bf(p[t][reg]);
            }
        f32x4 av[2]; av[0] = zf; av[1] = zf;
        #pragma unroll
        for (int kst = 0; kst < 2; ++kst) {
            short8 pa;
            { int row = wv*16+l15; int byt = row*128 + ((kst*64+l4*16) ^ ((row&7)<<4));
              pa = *(const short8*)&SL[PSo + (byt>>1)]; }
            #pragma unroll
            for (int dt = 0; dt < 2; ++dt) {
                int d = dt*16+l15; int byt = d*128 + ((kst*64+l4*16) ^ ((d&7)<<4));
                short8 bv = *(const short8*)&SL[VTo + (byt>>1)];
                av[dt] = __builtin_amdgcn_mfma_f32_16x16x32_bf16(pa, bv, av[dt], 0, 0, 0);
            }
        }
        __syncthreads();
        #pragma unroll
        for (int dt = 0; dt < 2; ++dt)
            #pragma unroll
            for (int reg = 0; reg < 4; ++reg) {
                int row = wv*16 + l4*4 + reg;
                int byt = row*64 + (((dt*16+l15) << 1) ^ ((row&3)<<4));
                SL[QAo + (byt>>1)] = f2bf(av[dt][reg]);
            }
        __syncthreads();
        short8 aa;
        { int row = wv*16+l15; int byt = row*64 + ((l4*16) ^ ((row&3)<<4));
          aa = *(const short8*)&SL[QAo + (byt>>1)]; }
        #pragma unroll
        for (int nt = 0; nt < 24; ++nt) {
            short8 bp = gather_bf(proj_w, nt * 16 + l15, h * 32 + l4 * 8);
            pacc[nt] = __builtin_amdgcn_mfma_f32_16x16x32_bf16(aa, bp, pacc[nt], 0, 0, 0);
        }
    }
    {
        float* op = out + xbase;
        #pragma unroll
        for (int nt = 0; nt < 24; ++nt) {
            const float pb = proj_b[nt * 16 + l15];
            #pragma unroll
            for (int reg = 0; reg < 4; ++reg) {
                const int i = wv * 16 + l4 * 4 + reg;
                if (i < NTOK) op[i * DIMC + nt * 16 + l15] = pacc[nt][reg] + pb;
            }
        }
    }
}

extern "C" void kernel_launch(void* const* d_in, const int* in_sizes, int n_in,
                              void* d_out, int out_size, void* d_ws, size_t ws_size,
                              hipStream_t stream) {
    const float* x          = (const float*)d_in[0];
    const float* mask       = (const float*)d_in[1];
    const float* qkv_w      = (const float*)d_in[2];
    const float* qkv_b      = (const float*)d_in[3];
    const float* proj_w     = (const float*)d_in[4];
    const float* proj_b     = (const float*)d_in[5];
    const float* bias_table = (const float*)d_in[6];
    float* out = (float*)d_out;

    const size_t need = (size_t)WQB_SHORTS * 2 + (size_t)WPB_SHORTS * 2 + AV_BYTES;
    if (ws_size >= need) {
        short* wqb = (short*)d_ws;
        short* wpb = wqb + WQB_SHORTS;
        char*  avb = (char*)(wpb + WPB_SHORTS);
        prep_weights<<<288, 256, 0, stream>>>(qkv_w, proj_w, wqb, wpb);
        winattn_fused<<<4096, 256, 0, stream>>>(x, mask, qkv_b, bias_table, wqb, avb);
        proj_gemm<<<MB_TILES * 3, 256, 0, stream>>>(avb, wpb, proj_b, out);
    } else {
        winattn_fallback<<<4096, 256, 0, stream>>>(x, mask, qkv_w, qkv_b, proj_w,
                                                   proj_b, bias_table, out);
    }
}